// Round 9
// baseline (7611.130 us; speedup 1.0000x reference)
//
#include <hip/hip_runtime.h>

#define S_ 160
#define B_ 64
#define H_ 1024
#define E_ 512
#define V_ 64
#define T_ 16
#define H4_ 4096
#define NBLK 256

__device__ __forceinline__ float sigm(float x) { return 1.f / (1.f + expf(-x)); }

// ---------------------------------------------------------------------------
// enc_t = enc_out @ enc_W^T + enc_b.  128x128 tile, BK=16, 8x8 acc/thread.
// (validated round 8)
// ---------------------------------------------------------------------------
__global__ __launch_bounds__(256) void gemm_bt_128(
    const float* __restrict__ A, const float* __restrict__ Bm,
    const float* __restrict__ bias, float* __restrict__ Cd,
    int M, int N, int K)
{
    __shared__ float As[16][132];
    __shared__ float Bs[16][132];
    const int bn = blockIdx.x, bm = blockIdx.y;
    const int tid = threadIdx.x;
    const int lr = tid >> 1, lk = (tid & 1) * 8;
    const int tx4 = (tid & 15) * 4, ty4 = (tid >> 4) * 4;
    const float* Ap = A + (size_t)(bm * 128 + lr) * K + lk;
    const float* Bp = Bm + (size_t)(bn * 128 + lr) * K + lk;
    float acc[8][8] = {};
    for (int k0 = 0; k0 < K; k0 += 16) {
        float4 a0 = *(const float4*)(Ap + k0);
        float4 a1 = *(const float4*)(Ap + k0 + 4);
        float4 b0 = *(const float4*)(Bp + k0);
        float4 b1 = *(const float4*)(Bp + k0 + 4);
        __syncthreads();
        As[lk + 0][lr] = a0.x; As[lk + 1][lr] = a0.y; As[lk + 2][lr] = a0.z; As[lk + 3][lr] = a0.w;
        As[lk + 4][lr] = a1.x; As[lk + 5][lr] = a1.y; As[lk + 6][lr] = a1.z; As[lk + 7][lr] = a1.w;
        Bs[lk + 0][lr] = b0.x; Bs[lk + 1][lr] = b0.y; Bs[lk + 2][lr] = b0.z; Bs[lk + 3][lr] = b0.w;
        Bs[lk + 4][lr] = b1.x; Bs[lk + 5][lr] = b1.y; Bs[lk + 6][lr] = b1.z; Bs[lk + 7][lr] = b1.w;
        __syncthreads();
#pragma unroll
        for (int kk = 0; kk < 16; ++kk) {
            float a[8], b[8];
            *(float4*)(a)     = *(const float4*)&As[kk][ty4];
            *(float4*)(a + 4) = *(const float4*)&As[kk][64 + ty4];
            *(float4*)(b)     = *(const float4*)&Bs[kk][tx4];
            *(float4*)(b + 4) = *(const float4*)&Bs[kk][64 + tx4];
#pragma unroll
            for (int i = 0; i < 8; ++i)
#pragma unroll
                for (int j = 0; j < 8; ++j) acc[i][j] = fmaf(a[i], b[j], acc[i][j]);
        }
    }
#pragma unroll
    for (int i = 0; i < 8; ++i) {
        int row = bm * 128 + ((i < 4) ? (ty4 + i) : (64 + ty4 + i - 4));
#pragma unroll
        for (int j = 0; j < 8; ++j) {
            int col = bn * 128 + ((j < 4) ? (tx4 + j) : (64 + tx4 + j - 4));
            Cd[(size_t)row * N + col] = acc[i][j] + bias[col];
        }
    }
}

// 64x64 tile GEMM helper (BK=16). Arow/Brow already offset by (lr*ld + lc).
__device__ __forceinline__ void tile64(const float* __restrict__ Arow,
                                       const float* __restrict__ Brow,
                                       int K, float acc[4][4],
                                       float* __restrict__ As,
                                       float* __restrict__ Bs)
{
    const int tid = threadIdx.x;
    const int lr = tid >> 2, lc = (tid & 3) << 2;
    const int tx = tid & 15, ty = tid >> 4;
    for (int k0 = 0; k0 < K; k0 += 16) {
        float4 av = *(const float4*)(Arow + k0);
        float4 bv = *(const float4*)(Brow + k0);
        __syncthreads();
        As[lr * 17 + lc + 0] = av.x; As[lr * 17 + lc + 1] = av.y;
        As[lr * 17 + lc + 2] = av.z; As[lr * 17 + lc + 3] = av.w;
        Bs[lr * 17 + lc + 0] = bv.x; Bs[lr * 17 + lc + 1] = bv.y;
        Bs[lr * 17 + lc + 2] = bv.z; Bs[lr * 17 + lc + 3] = bv.w;
        __syncthreads();
#pragma unroll
        for (int kk = 0; kk < 16; ++kk) {
            float a[4], b[4];
#pragma unroll
            for (int i = 0; i < 4; ++i) a[i] = As[(ty * 4 + i) * 17 + kk];
#pragma unroll
            for (int j = 0; j < 4; ++j) b[j] = Bs[(tx * 4 + j) * 17 + kk];
#pragma unroll
            for (int i = 0; i < 4; ++i)
#pragma unroll
                for (int j = 0; j < 4; ++j) acc[i][j] = fmaf(a[i], b[j], acc[i][j]);
        }
    }
    __syncthreads();
}

// Software grid barrier: 256 co-resident blocks, device-scope count + fences.
__device__ __forceinline__ void gridbar(unsigned* bar, unsigned target)
{
    __syncthreads();                 // drains each wave's vmem to L2
    if (threadIdx.x == 0) {
        __threadfence();             // cross-XCD publish (L2 writeback)
        atomicAdd(bar, 1u);          // device-scope
        while (__hip_atomic_load(bar, __ATOMIC_ACQUIRE, __HIP_MEMORY_SCOPE_AGENT) < target)
            __builtin_amdgcn_s_sleep(8);
        __threadfence();             // invalidate stale L1/L2 before reads
    }
    __syncthreads();
}

__global__ void zero_k(unsigned* bar) { if (threadIdx.x == 0) *bar = 0u; }

struct PP {
    const float *enc_h0, *enc_c0, *enc_out, *tok_emb, *embed;
    const float *W_ih, *b_ih, *b_hh, *out_W, *out_b, *dec_W, *dec_b;
    const float *attn_W, *attn_b, *W_hh;
    const int* lens;
    const float* enc_t;
    float *hh_gates, *out_h, *dec_part, *scores, *cur_emb, *part;
    unsigned* bar;
    float* out;
};

// ---------------------------------------------------------------------------
// Persistent kernel: hh_gates precompute + the entire T=16 decode loop.
// 256 blocks x 256 threads, phases separated by software grid barriers.
// ---------------------------------------------------------------------------
__global__ __launch_bounds__(256) void persist_k(PP p)
{
    __shared__ float smem[2448];     // 9.8 KB, phase-multiplexed
    const int tid = threadIdx.x, blk = blockIdx.x;
    const int lane = tid & 63, wv = tid >> 6;
    unsigned epoch = 0;
    float negent_r = 0.f, logp_r = 0.f;   // live in wave-0 lanes of blocks <64

    // ---- init cur_emb (doubles as phase work before first barrier) --------
    { int i = blk * 256 + tid; if (i < B_ * E_) p.cur_emb[i] = p.tok_emb[i & (E_ - 1)]; }

    // ---- hh partials: blk -> (bn = blk>>2 of 64, kz = blk&3), kLen=256 ----
    {
        const int bn = blk >> 2, kz = blk & 3;
        const int lr = tid >> 2, lc = (tid & 3) << 2;
        const int tx = tid & 15, ty = tid >> 4;
        float acc[4][4] = {};
        tile64(p.enc_h0 + (size_t)lr * H_ + kz * 256 + lc,
               p.W_hh + (size_t)(bn * 64 + lr) * H_ + kz * 256 + lc,
               256, acc, smem, smem + 1088);
        float* Cp = p.part + (size_t)kz * B_ * H4_;
#pragma unroll
        for (int i = 0; i < 4; ++i)
#pragma unroll
            for (int j = 0; j < 4; ++j)
                Cp[(size_t)(ty * 4 + i) * H4_ + bn * 64 + tx * 4 + j] = acc[i][j];
    }
    gridbar(p.bar, ++epoch * NBLK);

    // ---- hh reduce + biases ----------------------------------------------
    for (int idx = blk * 256 + tid; idx < B_ * H4_; idx += NBLK * 256) {
        float v = p.part[idx] + p.part[B_ * H4_ + idx]
                + p.part[2 * B_ * H4_ + idx] + p.part[3 * B_ * H4_ + idx];
        int col = idx & (H4_ - 1);
        p.hh_gates[idx] = v + p.b_ih[col] + p.b_hh[col];
    }
    gridbar(p.bar, ++epoch * NBLK);

    for (int t = 0; t < T_; ++t) {
        // ---- gates GEMM + LSTM: hs4 = blk*4 (validated round 8) ----------
        {
            float (*As2)[68] = (float(*)[68])smem;
            float (*Bs2)[17] = (float(*)[17])(smem + 1088);
            float (*gbuf)[17] = (float(*)[17])(smem + 1360);
            const int hs4 = blk * 4;
            const int c = tid & 15, rq = tid >> 4;
            const int colg = (c >> 2) * H_ + hs4 + (c & 3);
            const int kk_s = tid & 15, cs = tid >> 4;
            const int colg_s = (cs >> 2) * H_ + hs4 + (cs & 3);
            float acc[4] = {};
            for (int k0 = 0; k0 < E_; k0 += 16) {
                float a0 = p.cur_emb[(size_t)(cs     ) * E_ + k0 + kk_s];
                float a1 = p.cur_emb[(size_t)(cs + 16) * E_ + k0 + kk_s];
                float a2 = p.cur_emb[(size_t)(cs + 32) * E_ + k0 + kk_s];
                float a3 = p.cur_emb[(size_t)(cs + 48) * E_ + k0 + kk_s];
                float bv = p.W_ih[(size_t)colg_s * E_ + k0 + kk_s];
                __syncthreads();
                As2[kk_s][cs] = a0; As2[kk_s][cs + 16] = a1;
                As2[kk_s][cs + 32] = a2; As2[kk_s][cs + 48] = a3;
                Bs2[kk_s][cs] = bv;
                __syncthreads();
#pragma unroll
                for (int kk = 0; kk < 16; ++kk) {
                    float4 a4 = *(const float4*)&As2[kk][rq * 4];
                    float b = Bs2[kk][c];
                    acc[0] = fmaf(a4.x, b, acc[0]);
                    acc[1] = fmaf(a4.y, b, acc[1]);
                    acc[2] = fmaf(a4.z, b, acc[2]);
                    acc[3] = fmaf(a4.w, b, acc[3]);
                }
            }
            __syncthreads();
#pragma unroll
            for (int i = 0; i < 4; ++i)
                gbuf[rq * 4 + i][c] = acc[i] + p.hh_gates[(size_t)(rq * 4 + i) * H4_ + colg];
            __syncthreads();
            const int row = tid >> 2, w2 = tid & 3;
            float gi = gbuf[row][0 + w2], gf = gbuf[row][4 + w2];
            float gg = gbuf[row][8 + w2], go = gbuf[row][12 + w2];
            float c0v = p.enc_c0[(size_t)row * H_ + hs4 + w2];
            float cc = sigm(gf) * c0v + sigm(gi) * tanhf(gg);
            p.out_h[(size_t)row * H_ + hs4 + w2] = sigm(go) * tanhf(cc);
        }
        gridbar(p.bar, ++epoch * NBLK);

        // ---- dec_t split-K partials: blocks 0..63 ------------------------
        if (blk < 64) {
            const int bn = blk >> 2, kz = blk & 3;   // bn 0..15, kz 0..3
            const int lr = tid >> 2, lc = (tid & 3) << 2;
            const int tx = tid & 15, ty = tid >> 4;
            float acc[4][4] = {};
            tile64(p.out_h + (size_t)lr * H_ + kz * 256 + lc,
                   p.dec_W + (size_t)(bn * 64 + lr) * H_ + kz * 256 + lc,
                   256, acc, smem, smem + 1088);
            float* Cp = p.dec_part + (size_t)kz * B_ * H_;
#pragma unroll
            for (int i = 0; i < 4; ++i)
#pragma unroll
                for (int j = 0; j < 4; ++j)
                    Cp[(size_t)(ty * 4 + i) * H_ + bn * 64 + tx * 4 + j] = acc[i][j];
        }
        gridbar(p.bar, ++epoch * NBLK);

        // ---- scores: 1024 waves, wave (b, sg) does 10 s ------------------
        {
            const int gw = blk * 4 + wv;
            const int b = gw >> 4, sg = gw & 15;
            float dec_r[16], aw_r[16];
#pragma unroll
            for (int it = 0; it < 16; ++it) {
                int h = lane + it * 64;
                dec_r[it] = p.dec_part[(size_t)b * H_ + h]
                          + p.dec_part[(size_t)(B_ + b) * H_ + h]
                          + p.dec_part[(size_t)(2 * B_ + b) * H_ + h]
                          + p.dec_part[(size_t)(3 * B_ + b) * H_ + h]
                          + p.dec_b[h];
                aw_r[it] = p.attn_W[h];
            }
            const int len = p.lens[b];
            const float ab = p.attn_b[0];
            for (int s = sg * 10; s < sg * 10 + 10; ++s) {
                if (s >= len) { if (lane == 0) p.scores[b * S_ + s] = -1e9f; continue; }
                const float* eptr = p.enc_t + ((size_t)s * B_ + b) * H_;
                float acc = 0.f;
#pragma unroll
                for (int it = 0; it < 16; ++it)
                    acc += aw_r[it] * tanhf(eptr[lane + it * 64] + dec_r[it]);
                for (int d = 32; d; d >>= 1) acc += __shfl_xor(acc, d);
                if (lane == 0) p.scores[b * S_ + s] = acc + ab;
            }
        }
        gridbar(p.bar, ++epoch * NBLK);

        // ---- softmax + attn-out + context + logits + argmax + embed ------
        if (blk < 64) {
            const int b = blk;
            float* sc = smem;               // 160
            float* comb = smem + 160;       // 2048
            float* lg = smem + 2208;        // 64
            int* tokp = (int*)(smem + 2272);
            if (wv == 0) {
                float m = -1e30f;
                for (int s = lane; s < S_; s += 64) {
                    float v = p.scores[b * S_ + s]; sc[s] = v; m = fmaxf(m, v);
                }
                for (int d = 32; d; d >>= 1) m = fmaxf(m, __shfl_xor(m, d));
                float sum = 0.f;
                for (int s = lane; s < S_; s += 64) {
                    float e = expf(sc[s] - m); sc[s] = e; sum += e;
                }
                for (int d = 32; d; d >>= 1) sum += __shfl_xor(sum, d);
                float inv = 1.f / sum;
                for (int s = lane; s < S_; s += 64) {
                    float pr = sc[s] * inv; sc[s] = pr;
                    p.out[T_ * B_ + ((size_t)b * T_ + t) * S_ + s] = pr;
                }
            }
            __syncthreads();
            {   // context: 4 h per thread, float4, 4-way ILP
                const float* base = p.enc_out + (size_t)b * H_ + tid * 4;
                float4 ac0 = {0,0,0,0}, ac1 = {0,0,0,0}, ac2 = {0,0,0,0}, ac3 = {0,0,0,0};
#pragma unroll 4
                for (int s = 0; s < S_; s += 4) {
                    float4 e0 = *(const float4*)(base + (size_t)(s    ) * B_ * H_);
                    float4 e1 = *(const float4*)(base + (size_t)(s + 1) * B_ * H_);
                    float4 e2 = *(const float4*)(base + (size_t)(s + 2) * B_ * H_);
                    float4 e3 = *(const float4*)(base + (size_t)(s + 3) * B_ * H_);
                    float p0 = sc[s], p1 = sc[s + 1], p2 = sc[s + 2], p3 = sc[s + 3];
                    ac0.x = fmaf(p0, e0.x, ac0.x); ac0.y = fmaf(p0, e0.y, ac0.y);
                    ac0.z = fmaf(p0, e0.z, ac0.z); ac0.w = fmaf(p0, e0.w, ac0.w);
                    ac1.x = fmaf(p1, e1.x, ac1.x); ac1.y = fmaf(p1, e1.y, ac1.y);
                    ac1.z = fmaf(p1, e1.z, ac1.z); ac1.w = fmaf(p1, e1.w, ac1.w);
                    ac2.x = fmaf(p2, e2.x, ac2.x); ac2.y = fmaf(p2, e2.y, ac2.y);
                    ac2.z = fmaf(p2, e2.z, ac2.z); ac2.w = fmaf(p2, e2.w, ac2.w);
                    ac3.x = fmaf(p3, e3.x, ac3.x); ac3.y = fmaf(p3, e3.y, ac3.y);
                    ac3.z = fmaf(p3, e3.z, ac3.z); ac3.w = fmaf(p3, e3.w, ac3.w);
                }
                comb[tid * 4 + 0] = ac0.x + ac1.x + ac2.x + ac3.x;
                comb[tid * 4 + 1] = ac0.y + ac1.y + ac2.y + ac3.y;
                comb[tid * 4 + 2] = ac0.z + ac1.z + ac2.z + ac3.z;
                comb[tid * 4 + 3] = ac0.w + ac1.w + ac2.w + ac3.w;
            }
            for (int i = tid; i < H_; i += 256) comb[H_ + i] = p.out_h[(size_t)b * H_ + i];
            __syncthreads();
            for (int v = wv * 16; v < wv * 16 + 16; ++v) {
                const float* w = p.out_W + (size_t)v * (2 * H_);
                float a0 = 0.f, a1 = 0.f;
#pragma unroll
                for (int j = 0; j < 32; j += 2) {
                    a0 = fmaf(comb[lane + j * 64], w[lane + j * 64], a0);
                    a1 = fmaf(comb[lane + (j + 1) * 64], w[lane + (j + 1) * 64], a1);
                }
                float acc = a0 + a1;
                for (int d = 32; d; d >>= 1) acc += __shfl_xor(acc, d);
                if (lane == 0) lg[v] = acc + p.out_b[v];
            }
            __syncthreads();
            if (wv == 0) {
                float x = lg[lane];
                float m = x;
                for (int d = 32; d; d >>= 1) m = fmaxf(m, __shfl_xor(m, d));
                float e = expf(x - m);
                float s = e;
                for (int d = 32; d; d >>= 1) s += __shfl_xor(s, d);
                float pr = e / s;
                float ps = pr;
                for (int d = 32; d; d >>= 1) ps += __shfl_xor(ps, d);
                pr = pr / ps;   // reference renormalizes
                float bv = pr; int bi = lane;
                for (int d = 32; d; d >>= 1) {
                    float ov = __shfl_xor(bv, d); int oi = __shfl_xor(bi, d);
                    if (ov > bv || (ov == bv && oi < bi)) { bv = ov; bi = oi; }
                }
                float ne = pr * logf(pr + 1e-6f);
                for (int d = 32; d; d >>= 1) ne += __shfl_xor(ne, d);
                float ptok = __shfl(pr, bi);
                negent_r += ne;                  // all wave-0 lanes identical
                logp_r += logf(ptok + 1e-6f);
                if (lane == 0) {
                    p.out[t * B_ + b] = (float)bi;
                    if (t == T_ - 1) {
                        p.out[T_ * B_ + B_ * T_ * S_ + b] = negent_r;
                        p.out[T_ * B_ + B_ * T_ * S_ + B_ + b] = logp_r;
                    }
                    *tokp = bi;
                }
            }
            __syncthreads();
            const int tok = *tokp;
            for (int i = tid; i < E_; i += 256)
                p.cur_emb[(size_t)b * E_ + i] = p.embed[(size_t)tok * E_ + i];
        }
        if (t < T_ - 1) gridbar(p.bar, ++epoch * NBLK);
    }
}

extern "C" void kernel_launch(void* const* d_in, const int* in_sizes, int n_in,
                              void* d_out, int out_size, void* d_ws, size_t ws_size,
                              hipStream_t stream) {
    PP P;
    P.enc_h0  = (const float*)d_in[0];
    P.enc_c0  = (const float*)d_in[1];
    P.enc_out = (const float*)d_in[2];
    P.lens    = (const int*)d_in[3];
    P.tok_emb = (const float*)d_in[4];
    P.embed   = (const float*)d_in[5];
    P.W_ih    = (const float*)d_in[6];
    P.W_hh    = (const float*)d_in[7];
    P.b_ih    = (const float*)d_in[8];
    P.b_hh    = (const float*)d_in[9];
    P.out_W   = (const float*)d_in[10];
    P.out_b   = (const float*)d_in[11];
    const float* enc_W = (const float*)d_in[12];
    const float* enc_b = (const float*)d_in[13];
    P.dec_W   = (const float*)d_in[14];
    P.dec_b   = (const float*)d_in[15];
    P.attn_W  = (const float*)d_in[16];
    P.attn_b  = (const float*)d_in[17];
    P.out = (float*)d_out;

    // ws layout (floats)
    float* ws = (float*)d_ws;
    P.hh_gates = ws;                            // 262144
    P.out_h    = P.hh_gates + B_ * H4_;         // 65536
    P.dec_part = P.out_h + B_ * H_;             // 262144
    P.scores   = P.dec_part + 4 * B_ * H_;      // 10240
    P.cur_emb  = P.scores + B_ * S_;            // 32768
    P.part     = P.cur_emb + B_ * E_;           // 1048576 (4 x B x 4H)
    float* enc_t = P.part + (size_t)4 * B_ * H4_;   // 10485760
    P.enc_t = enc_t;
    P.bar = (unsigned*)(enc_t + (size_t)S_ * B_ * H_);   // 64 B
    // total = 12,167,232 floats = 48,668,928 B  (ws_size known >= 49,152,512)
    if (ws_size < 48668992u) return;

    zero_k<<<1, 64, 0, stream>>>(P.bar);
    gemm_bt_128<<<dim3(H_ / 128, (S_ * B_) / 128), 256, 0, stream>>>(
        P.enc_out, enc_W, enc_b, (float*)enc_t, S_ * B_, H_, H_);
    persist_k<<<NBLK, 256, 0, stream>>>(P);
}

// Round 10
// 5373.378 us; speedup vs baseline: 1.4165x; 1.4165x over previous
//
#include <hip/hip_runtime.h>

#define S_ 160
#define B_ 64
#define H_ 1024
#define E_ 512
#define V_ 64
#define T_ 16
#define H4_ 4096

__device__ __forceinline__ float sigm(float x) { return 1.f / (1.f + expf(-x)); }

// ---------------------------------------------------------------------------
// enc_t = enc_out @ enc_W^T + enc_b.  128x128 tile, BK=16, 8x8 acc/thread.
// (validated round 8)
// ---------------------------------------------------------------------------
__global__ __launch_bounds__(256) void gemm_bt_128(
    const float* __restrict__ A, const float* __restrict__ Bm,
    const float* __restrict__ bias, float* __restrict__ Cd,
    int M, int N, int K)
{
    __shared__ float As[16][132];
    __shared__ float Bs[16][132];
    const int bn = blockIdx.x, bm = blockIdx.y;
    const int tid = threadIdx.x;
    const int lr = tid >> 1, lk = (tid & 1) * 8;
    const int tx4 = (tid & 15) * 4, ty4 = (tid >> 4) * 4;
    const float* Ap = A + (size_t)(bm * 128 + lr) * K + lk;
    const float* Bp = Bm + (size_t)(bn * 128 + lr) * K + lk;
    float acc[8][8] = {};
    for (int k0 = 0; k0 < K; k0 += 16) {
        float4 a0 = *(const float4*)(Ap + k0);
        float4 a1 = *(const float4*)(Ap + k0 + 4);
        float4 b0 = *(const float4*)(Bp + k0);
        float4 b1 = *(const float4*)(Bp + k0 + 4);
        __syncthreads();
        As[lk + 0][lr] = a0.x; As[lk + 1][lr] = a0.y; As[lk + 2][lr] = a0.z; As[lk + 3][lr] = a0.w;
        As[lk + 4][lr] = a1.x; As[lk + 5][lr] = a1.y; As[lk + 6][lr] = a1.z; As[lk + 7][lr] = a1.w;
        Bs[lk + 0][lr] = b0.x; Bs[lk + 1][lr] = b0.y; Bs[lk + 2][lr] = b0.z; Bs[lk + 3][lr] = b0.w;
        Bs[lk + 4][lr] = b1.x; Bs[lk + 5][lr] = b1.y; Bs[lk + 6][lr] = b1.z; Bs[lk + 7][lr] = b1.w;
        __syncthreads();
#pragma unroll
        for (int kk = 0; kk < 16; ++kk) {
            float a[8], b[8];
            *(float4*)(a)     = *(const float4*)&As[kk][ty4];
            *(float4*)(a + 4) = *(const float4*)&As[kk][64 + ty4];
            *(float4*)(b)     = *(const float4*)&Bs[kk][tx4];
            *(float4*)(b + 4) = *(const float4*)&Bs[kk][64 + tx4];
#pragma unroll
            for (int i = 0; i < 8; ++i)
#pragma unroll
                for (int j = 0; j < 8; ++j) acc[i][j] = fmaf(a[i], b[j], acc[i][j]);
        }
    }
#pragma unroll
    for (int i = 0; i < 8; ++i) {
        int row = bm * 128 + ((i < 4) ? (ty4 + i) : (64 + ty4 + i - 4));
#pragma unroll
        for (int j = 0; j < 8; ++j) {
            int col = bn * 128 + ((j < 4) ? (tx4 + j) : (64 + tx4 + j - 4));
            Cd[(size_t)row * N + col] = acc[i][j] + bias[col];
        }
    }
}

// 64x64 tile GEMM helper (BK=16). Arow/Brow already offset by (lr*ld + lc).
__device__ __forceinline__ void tile64(const float* __restrict__ Arow,
                                       const float* __restrict__ Brow,
                                       int K, float acc[4][4],
                                       float* __restrict__ As,
                                       float* __restrict__ Bs)
{
    const int tid = threadIdx.x;
    const int lr = tid >> 2, lc = (tid & 3) << 2;
    const int tx = tid & 15, ty = tid >> 4;
    for (int k0 = 0; k0 < K; k0 += 16) {
        float4 av = *(const float4*)(Arow + k0);
        float4 bv = *(const float4*)(Brow + k0);
        __syncthreads();
        As[lr * 17 + lc + 0] = av.x; As[lr * 17 + lc + 1] = av.y;
        As[lr * 17 + lc + 2] = av.z; As[lr * 17 + lc + 3] = av.w;
        Bs[lr * 17 + lc + 0] = bv.x; Bs[lr * 17 + lc + 1] = bv.y;
        Bs[lr * 17 + lc + 2] = bv.z; Bs[lr * 17 + lc + 3] = bv.w;
        __syncthreads();
#pragma unroll
        for (int kk = 0; kk < 16; ++kk) {
            float a[4], b[4];
#pragma unroll
            for (int i = 0; i < 4; ++i) a[i] = As[(ty * 4 + i) * 17 + kk];
#pragma unroll
            for (int j = 0; j < 4; ++j) b[j] = Bs[(tx * 4 + j) * 17 + kk];
#pragma unroll
            for (int i = 0; i < 4; ++i)
#pragma unroll
                for (int j = 0; j < 4; ++j) acc[i][j] = fmaf(a[i], b[j], acc[i][j]);
        }
    }
    __syncthreads();
}

// Split-K partials: Cpart[kz][M][N] (validated). KS==1 -> plain GEMM to Cpart.
__global__ __launch_bounds__(256) void gemm_part(
    const float* __restrict__ A, const float* __restrict__ Bm,
    float* __restrict__ Cpart, int M, int N, int K)
{
    __shared__ float smem[2176];
    const int bn = blockIdx.x, bm = blockIdx.y, kz = blockIdx.z, KS = gridDim.z;
    const int tid = threadIdx.x;
    const int lr = tid >> 2, lc = (tid & 3) << 2;
    const int tx = tid & 15, ty = tid >> 4;
    const int kLen = K / KS, k0base = kz * kLen;
    float acc[4][4] = {};
    tile64(A + (size_t)(bm * 64 + lr) * K + k0base + lc,
           Bm + (size_t)(bn * 64 + lr) * K + k0base + lc,
           kLen, acc, smem, smem + 1088);
    float* Cp = Cpart + (size_t)kz * M * N;
#pragma unroll
    for (int i = 0; i < 4; ++i) {
        int row = bm * 64 + ty * 4 + i;
#pragma unroll
        for (int j = 0; j < 4; ++j)
            Cp[(size_t)row * N + bn * 64 + tx * 4 + j] = acc[i][j];
    }
}

__global__ void reduce_partials(const float* __restrict__ Cpart, int KS,
                                const float* __restrict__ bias,
                                const float* __restrict__ bias2,
                                float* __restrict__ C, int MN, int N)
{
    int idx = blockIdx.x * 256 + threadIdx.x;
    if (idx >= MN) return;
    float v = 0.f;
    for (int z = 0; z < KS; ++z) v += Cpart[(size_t)z * MN + idx];
    int col = idx % N;
    if (bias)  v += bias[col];
    if (bias2) v += bias2[col];
    C[idx] = v;
}

// Build emb_ext (rows 0..63 = embed, row 64 = tok_emb, 65..127 = 0);
// init tok=64 (SOS), negent/logp accumulators.
__global__ void init_k(const float* __restrict__ embed, const float* __restrict__ tok_emb,
                       float* __restrict__ emb_ext, int* __restrict__ tok,
                       float* __restrict__ negent, float* __restrict__ logp)
{
    int i = blockIdx.x * 256 + threadIdx.x;
    if (i < 128 * E_) {
        int r = i >> 9, c = i & (E_ - 1);
        emb_ext[i] = (r < 64) ? embed[r * E_ + c] : ((r == 64) ? tok_emb[c] : 0.f);
    }
    if (i < B_) { tok[i] = 64; negent[i] = 0.f; logp[i] = 0.f; }
}

// ---------------------------------------------------------------------------
// Fused LSTM (from precomputed all_gates gather) + dec split-K GEMM tile.
// 64 blocks = (bn 0..15, kz 0..3). out_h slice computed in LDS (16x redundant
// across bn, trivially cheap); bn==0 blocks also publish out_h to global.
// ---------------------------------------------------------------------------
__global__ __launch_bounds__(256) void dec_lstm_k(
    const float* __restrict__ all_gates, const float* __restrict__ hh_gates,
    const int* __restrict__ tok, const float* __restrict__ enc_c0,
    const float* __restrict__ dec_W, float* __restrict__ out_h,
    float* __restrict__ dec_part)
{
    __shared__ float Ah[64][257];   // out_h slice [b][k], pad 257 (bank-clean)
    __shared__ float Bs[64][17];
    const int tid = threadIdx.x;
    const int bn = blockIdx.x >> 2, kz = blockIdx.x & 3;
    const int k0base = kz * 256;
    const int h = k0base + tid;     // tid = hh (0..255)
    for (int b = 0; b < 64; ++b) {
        const float* ag = all_gates + (size_t)tok[b] * H4_;
        const float* hg = hh_gates + (size_t)b * H4_;
        float gi = ag[h] + hg[h];
        float gf = ag[H_ + h] + hg[H_ + h];
        float gg = ag[2 * H_ + h] + hg[2 * H_ + h];
        float go = ag[3 * H_ + h] + hg[3 * H_ + h];
        float cc = sigm(gf) * enc_c0[b * H_ + h] + sigm(gi) * tanhf(gg);
        float oh = sigm(go) * tanhf(cc);
        Ah[b][tid] = oh;
        if (bn == 0) out_h[(size_t)b * H_ + h] = oh;
    }
    __syncthreads();
    const int lr = tid >> 2, lc = (tid & 3) << 2;
    const int tx = tid & 15, ty = tid >> 4;
    const float* Bp = dec_W + (size_t)(bn * 64 + lr) * H_ + k0base + lc;
    float acc[4][4] = {};
    for (int k0 = 0; k0 < 256; k0 += 16) {
        float4 bv = *(const float4*)(Bp + k0);
        __syncthreads();
        Bs[lr][lc] = bv.x; Bs[lr][lc + 1] = bv.y;
        Bs[lr][lc + 2] = bv.z; Bs[lr][lc + 3] = bv.w;
        __syncthreads();
#pragma unroll
        for (int kk = 0; kk < 16; ++kk) {
            float a[4], b4[4];
#pragma unroll
            for (int i = 0; i < 4; ++i) a[i] = Ah[ty * 4 + i][k0 + kk];
#pragma unroll
            for (int j = 0; j < 4; ++j) b4[j] = Bs[tx * 4 + j][kk];
#pragma unroll
            for (int i = 0; i < 4; ++i)
#pragma unroll
                for (int j = 0; j < 4; ++j) acc[i][j] = fmaf(a[i], b4[j], acc[i][j]);
        }
    }
    float* Cp = dec_part + (size_t)kz * B_ * H_;
#pragma unroll
    for (int i = 0; i < 4; ++i)
#pragma unroll
        for (int j = 0; j < 4; ++j)
            Cp[(size_t)(ty * 4 + i) * H_ + bn * 64 + tx * 4 + j] = acc[i][j];
}

// ---------------------------------------------------------------------------
// Fused per-b tail: scores (4 waves x 40 s, dec partial-sum + dec_b in regs)
// + masked softmax + attn-map out + context (float4 ILP) + logits + renorm
// softmax + argmax + stats + next-token write. One block per b.
// ---------------------------------------------------------------------------
__global__ __launch_bounds__(256) void score_smax_k(
    const float* __restrict__ enc_t, const float* __restrict__ dec_part,
    const float* __restrict__ dec_b, const float* __restrict__ attn_W,
    const float* __restrict__ attn_b, const int* __restrict__ lens,
    const float* __restrict__ enc_out, const float* __restrict__ out_h,
    const float* __restrict__ out_W, const float* __restrict__ out_b,
    float* __restrict__ negent_acc, float* __restrict__ logp_acc,
    int* __restrict__ tok, float* __restrict__ out, int t)
{
    __shared__ float sc[S_];
    __shared__ float comb[2 * H_];
    __shared__ float lg[V_];
    __shared__ int tokp;
    const int tid = threadIdx.x;
    const int b = blockIdx.x;
    const int lane = tid & 63, wv = tid >> 6;
    {   // ---- scores ----
        float dec_r[16], aw_r[16];
#pragma unroll
        for (int it = 0; it < 16; ++it) {
            int hh = lane + it * 64;
            dec_r[it] = dec_part[(size_t)b * H_ + hh]
                      + dec_part[(size_t)(B_ + b) * H_ + hh]
                      + dec_part[(size_t)(2 * B_ + b) * H_ + hh]
                      + dec_part[(size_t)(3 * B_ + b) * H_ + hh]
                      + dec_b[hh];
            aw_r[it] = attn_W[hh];
        }
        const int len = lens[b];
        const float ab = attn_b[0];
        for (int s = wv; s < S_; s += 4) {
            if (s >= len) { if (lane == 0) sc[s] = -1e9f; continue; }
            const float* ep = enc_t + ((size_t)s * B_ + b) * H_;
            float acc = 0.f;
#pragma unroll
            for (int it = 0; it < 16; ++it)
                acc += aw_r[it] * tanhf(ep[lane + it * 64] + dec_r[it]);
            for (int d = 32; d; d >>= 1) acc += __shfl_xor(acc, d);
            if (lane == 0) sc[s] = acc + ab;
        }
    }
    __syncthreads();
    if (wv == 0) {   // ---- masked softmax + attn-map out ----
        float m = -1e30f;
        for (int s = lane; s < S_; s += 64) m = fmaxf(m, sc[s]);
        for (int d = 32; d; d >>= 1) m = fmaxf(m, __shfl_xor(m, d));
        float sum = 0.f;
        for (int s = lane; s < S_; s += 64) {
            float e = expf(sc[s] - m); sc[s] = e; sum += e;
        }
        for (int d = 32; d; d >>= 1) sum += __shfl_xor(sum, d);
        float inv = 1.f / sum;
        for (int s = lane; s < S_; s += 64) {
            float pr = sc[s] * inv; sc[s] = pr;
            out[T_ * B_ + ((size_t)b * T_ + t) * S_ + s] = pr;
        }
    }
    __syncthreads();
    {   // ---- context: 4 h per thread, float4, 4-way ILP ----
        const float* base = enc_out + (size_t)b * H_ + tid * 4;
        float4 ac0 = {0,0,0,0}, ac1 = {0,0,0,0}, ac2 = {0,0,0,0}, ac3 = {0,0,0,0};
#pragma unroll 4
        for (int s = 0; s < S_; s += 4) {
            float4 e0 = *(const float4*)(base + (size_t)(s    ) * B_ * H_);
            float4 e1 = *(const float4*)(base + (size_t)(s + 1) * B_ * H_);
            float4 e2 = *(const float4*)(base + (size_t)(s + 2) * B_ * H_);
            float4 e3 = *(const float4*)(base + (size_t)(s + 3) * B_ * H_);
            float p0 = sc[s], p1 = sc[s + 1], p2 = sc[s + 2], p3 = sc[s + 3];
            ac0.x = fmaf(p0, e0.x, ac0.x); ac0.y = fmaf(p0, e0.y, ac0.y);
            ac0.z = fmaf(p0, e0.z, ac0.z); ac0.w = fmaf(p0, e0.w, ac0.w);
            ac1.x = fmaf(p1, e1.x, ac1.x); ac1.y = fmaf(p1, e1.y, ac1.y);
            ac1.z = fmaf(p1, e1.z, ac1.z); ac1.w = fmaf(p1, e1.w, ac1.w);
            ac2.x = fmaf(p2, e2.x, ac2.x); ac2.y = fmaf(p2, e2.y, ac2.y);
            ac2.z = fmaf(p2, e2.z, ac2.z); ac2.w = fmaf(p2, e2.w, ac2.w);
            ac3.x = fmaf(p3, e3.x, ac3.x); ac3.y = fmaf(p3, e3.y, ac3.y);
            ac3.z = fmaf(p3, e3.z, ac3.z); ac3.w = fmaf(p3, e3.w, ac3.w);
        }
        comb[tid * 4 + 0] = ac0.x + ac1.x + ac2.x + ac3.x;
        comb[tid * 4 + 1] = ac0.y + ac1.y + ac2.y + ac3.y;
        comb[tid * 4 + 2] = ac0.z + ac1.z + ac2.z + ac3.z;
        comb[tid * 4 + 3] = ac0.w + ac1.w + ac2.w + ac3.w;
    }
    for (int i = tid; i < H_; i += 256) comb[H_ + i] = out_h[(size_t)b * H_ + i];
    __syncthreads();
    for (int v = wv * 16; v < wv * 16 + 16; ++v) {   // ---- logits ----
        const float* w = out_W + (size_t)v * (2 * H_);
        float a0 = 0.f, a1 = 0.f;
#pragma unroll
        for (int j = 0; j < 32; j += 2) {
            a0 = fmaf(comb[lane + j * 64], w[lane + j * 64], a0);
            a1 = fmaf(comb[lane + (j + 1) * 64], w[lane + (j + 1) * 64], a1);
        }
        float acc = a0 + a1;
        for (int d = 32; d; d >>= 1) acc += __shfl_xor(acc, d);
        if (lane == 0) lg[v] = acc + out_b[v];
    }
    __syncthreads();
    if (wv == 0) {   // ---- softmax + renorm + argmax + stats ----
        float x = lg[lane];
        float m = x;
        for (int d = 32; d; d >>= 1) m = fmaxf(m, __shfl_xor(m, d));
        float e = expf(x - m);
        float s = e;
        for (int d = 32; d; d >>= 1) s += __shfl_xor(s, d);
        float pr = e / s;
        float ps = pr;
        for (int d = 32; d; d >>= 1) ps += __shfl_xor(ps, d);
        pr = pr / ps;   // reference renormalizes
        float bv = pr; int bi = lane;
        for (int d = 32; d; d >>= 1) {
            float ov = __shfl_xor(bv, d); int oi = __shfl_xor(bi, d);
            if (ov > bv || (ov == bv && oi < bi)) { bv = ov; bi = oi; }
        }
        float ne = pr * logf(pr + 1e-6f);
        for (int d = 32; d; d >>= 1) ne += __shfl_xor(ne, d);
        float ptok = __shfl(pr, bi);
        if (lane == 0) {
            out[t * B_ + b] = (float)bi;
            float na = negent_acc[b] + ne;                negent_acc[b] = na;
            float la = logp_acc[b] + logf(ptok + 1e-6f);  logp_acc[b] = la;
            if (t == T_ - 1) {
                out[T_ * B_ + B_ * T_ * S_ + b] = na;
                out[T_ * B_ + B_ * T_ * S_ + B_ + b] = la;
            }
            tok[b] = bi;   // next step's gather index
        }
    }
}

extern "C" void kernel_launch(void* const* d_in, const int* in_sizes, int n_in,
                              void* d_out, int out_size, void* d_ws, size_t ws_size,
                              hipStream_t stream) {
    const float* enc_h0  = (const float*)d_in[0];
    const float* enc_c0  = (const float*)d_in[1];
    const float* enc_out = (const float*)d_in[2];
    const int*   lens    = (const int*)d_in[3];
    const float* tok_emb = (const float*)d_in[4];
    const float* embed   = (const float*)d_in[5];
    const float* W_ih    = (const float*)d_in[6];
    const float* W_hh    = (const float*)d_in[7];
    const float* b_ih    = (const float*)d_in[8];
    const float* b_hh    = (const float*)d_in[9];
    const float* out_W   = (const float*)d_in[10];
    const float* out_b   = (const float*)d_in[11];
    const float* enc_W   = (const float*)d_in[12];
    const float* enc_b   = (const float*)d_in[13];
    const float* dec_W   = (const float*)d_in[14];
    const float* dec_b   = (const float*)d_in[15];
    const float* attn_W  = (const float*)d_in[16];
    const float* attn_b  = (const float*)d_in[17];
    float* out = (float*)d_out;

    // ws layout (floats). part aliases enc_t (consumed before enc_t written).
    float* ws = (float*)d_ws;
    float* hh_gates  = ws;                         // 262144
    float* out_h     = hh_gates + B_ * H4_;        // 65536
    float* dec_part  = out_h + B_ * H_;            // 262144
    float* negent    = dec_part + 4 * B_ * H_;     // 64
    float* logp      = negent + B_;                // 64
    int*   tok       = (int*)(logp + B_);          // 64
    float* emb_ext   = (float*)(tok + B_);         // 65536 (128 x 512)
    float* all_gates = emb_ext + 128 * E_;         // 524288 (128 x 4096)
    float* enc_t     = all_gates + (size_t)128 * H4_;  // 10485760
    float* part      = enc_t;                      // alias: 4 x B x 4H
    // total = 11,665,600 floats = 46,662,400 B (ws_size known >= 49,152,512)
    if (ws_size < 46662400u) return;

    init_k<<<(128 * E_ + 255) / 256, 256, 0, stream>>>(embed, tok_emb, emb_ext,
                                                       tok, negent, logp);

    // hh_gates = h0 @ W_hh^T + b_ih + b_hh (step-invariant)
    gemm_part<<<dim3(H4_ / 64, 1, 4), 256, 0, stream>>>(enc_h0, W_hh, part, B_, H4_, H_);
    reduce_partials<<<(B_ * H4_ + 255) / 256, 256, 0, stream>>>(
        part, 4, b_ih, b_hh, hh_gates, B_ * H4_, H4_);

    // all_gates = emb_ext @ W_ih^T (no bias; biases live in hh_gates)
    gemm_part<<<dim3(H4_ / 64, 2, 1), 256, 0, stream>>>(emb_ext, W_ih, all_gates,
                                                        128, H4_, E_);

    // enc_t = encoder_outputs @ enc_W^T + enc_b (after part consumed)
    gemm_bt_128<<<dim3(H_ / 128, (S_ * B_) / 128), 256, 0, stream>>>(
        enc_out, enc_W, enc_b, enc_t, S_ * B_, H_, H_);

    for (int t = 0; t < T_; ++t) {
        dec_lstm_k<<<64, 256, 0, stream>>>(all_gates, hh_gates, tok, enc_c0, dec_W,
                                           out_h, dec_part);
        score_smax_k<<<64, 256, 0, stream>>>(enc_t, dec_part, dec_b, attn_W, attn_b,
                                             lens, enc_out, out_h, out_W, out_b,
                                             negent, logp, tok, out, t);
    }
}

// Round 12
// 1628.856 us; speedup vs baseline: 4.6727x; 3.2989x over previous
//
#include <hip/hip_runtime.h>

#define S_ 160
#define B_ 64
#define H_ 1024
#define E_ 512
#define V_ 64
#define T_ 16
#define H4_ 4096

__device__ __forceinline__ float sigm(float x) { return 1.f / (1.f + expf(-x)); }

// ---------------------------------------------------------------------------
// enc_t = enc_out @ enc_W^T + enc_b.  128x128 tile, BK=16, 8x8 acc/thread.
// (validated round 8)
// ---------------------------------------------------------------------------
__global__ __launch_bounds__(256) void gemm_bt_128(
    const float* __restrict__ A, const float* __restrict__ Bm,
    const float* __restrict__ bias, float* __restrict__ Cd,
    int M, int N, int K)
{
    __shared__ float As[16][132];
    __shared__ float Bs[16][132];
    const int bn = blockIdx.x, bm = blockIdx.y;
    const int tid = threadIdx.x;
    const int lr = tid >> 1, lk = (tid & 1) * 8;
    const int tx4 = (tid & 15) * 4, ty4 = (tid >> 4) * 4;
    const float* Ap = A + (size_t)(bm * 128 + lr) * K + lk;
    const float* Bp = Bm + (size_t)(bn * 128 + lr) * K + lk;
    float acc[8][8] = {};
    for (int k0 = 0; k0 < K; k0 += 16) {
        float4 a0 = *(const float4*)(Ap + k0);
        float4 a1 = *(const float4*)(Ap + k0 + 4);
        float4 b0 = *(const float4*)(Bp + k0);
        float4 b1 = *(const float4*)(Bp + k0 + 4);
        __syncthreads();
        As[lk + 0][lr] = a0.x; As[lk + 1][lr] = a0.y; As[lk + 2][lr] = a0.z; As[lk + 3][lr] = a0.w;
        As[lk + 4][lr] = a1.x; As[lk + 5][lr] = a1.y; As[lk + 6][lr] = a1.z; As[lk + 7][lr] = a1.w;
        Bs[lk + 0][lr] = b0.x; Bs[lk + 1][lr] = b0.y; Bs[lk + 2][lr] = b0.z; Bs[lk + 3][lr] = b0.w;
        Bs[lk + 4][lr] = b1.x; Bs[lk + 5][lr] = b1.y; Bs[lk + 6][lr] = b1.z; Bs[lk + 7][lr] = b1.w;
        __syncthreads();
#pragma unroll
        for (int kk = 0; kk < 16; ++kk) {
            float a[8], b[8];
            *(float4*)(a)     = *(const float4*)&As[kk][ty4];
            *(float4*)(a + 4) = *(const float4*)&As[kk][64 + ty4];
            *(float4*)(b)     = *(const float4*)&Bs[kk][tx4];
            *(float4*)(b + 4) = *(const float4*)&Bs[kk][64 + tx4];
#pragma unroll
            for (int i = 0; i < 8; ++i)
#pragma unroll
                for (int j = 0; j < 8; ++j) acc[i][j] = fmaf(a[i], b[j], acc[i][j]);
        }
    }
#pragma unroll
    for (int i = 0; i < 8; ++i) {
        int row = bm * 128 + ((i < 4) ? (ty4 + i) : (64 + ty4 + i - 4));
#pragma unroll
        for (int j = 0; j < 8; ++j) {
            int col = bn * 128 + ((j < 4) ? (tx4 + j) : (64 + tx4 + j - 4));
            Cd[(size_t)row * N + col] = acc[i][j] + bias[col];
        }
    }
}

// 64x64 tile GEMM helper (BK=16). Arow/Brow already offset by (lr*ld + lc).
__device__ __forceinline__ void tile64(const float* __restrict__ Arow,
                                       const float* __restrict__ Brow,
                                       int K, float acc[4][4],
                                       float* __restrict__ As,
                                       float* __restrict__ Bs)
{
    const int tid = threadIdx.x;
    const int lr = tid >> 2, lc = (tid & 3) << 2;
    const int tx = tid & 15, ty = tid >> 4;
    for (int k0 = 0; k0 < K; k0 += 16) {
        float4 av = *(const float4*)(Arow + k0);
        float4 bv = *(const float4*)(Brow + k0);
        __syncthreads();
        As[lr * 17 + lc + 0] = av.x; As[lr * 17 + lc + 1] = av.y;
        As[lr * 17 + lc + 2] = av.z; As[lr * 17 + lc + 3] = av.w;
        Bs[lr * 17 + lc + 0] = bv.x; Bs[lr * 17 + lc + 1] = bv.y;
        Bs[lr * 17 + lc + 2] = bv.z; Bs[lr * 17 + lc + 3] = bv.w;
        __syncthreads();
#pragma unroll
        for (int kk = 0; kk < 16; ++kk) {
            float a[4], b[4];
#pragma unroll
            for (int i = 0; i < 4; ++i) a[i] = As[(ty * 4 + i) * 17 + kk];
#pragma unroll
            for (int j = 0; j < 4; ++j) b[j] = Bs[(tx * 4 + j) * 17 + kk];
#pragma unroll
            for (int i = 0; i < 4; ++i)
#pragma unroll
                for (int j = 0; j < 4; ++j) acc[i][j] = fmaf(a[i], b[j], acc[i][j]);
        }
    }
    __syncthreads();
}

// Split-K partials: Cpart[kz][M][N] (validated). KS==1 -> plain GEMM to Cpart.
__global__ __launch_bounds__(256) void gemm_part(
    const float* __restrict__ A, const float* __restrict__ Bm,
    float* __restrict__ Cpart, int M, int N, int K)
{
    __shared__ float smem[2176];
    const int bn = blockIdx.x, bm = blockIdx.y, kz = blockIdx.z, KS = gridDim.z;
    const int tid = threadIdx.x;
    const int lr = tid >> 2, lc = (tid & 3) << 2;
    const int tx = tid & 15, ty = tid >> 4;
    const int kLen = K / KS, k0base = kz * kLen;
    float acc[4][4] = {};
    tile64(A + (size_t)(bm * 64 + lr) * K + k0base + lc,
           Bm + (size_t)(bn * 64 + lr) * K + k0base + lc,
           kLen, acc, smem, smem + 1088);
    float* Cp = Cpart + (size_t)kz * M * N;
#pragma unroll
    for (int i = 0; i < 4; ++i) {
        int row = bm * 64 + ty * 4 + i;
#pragma unroll
        for (int j = 0; j < 4; ++j)
            Cp[(size_t)row * N + bn * 64 + tx * 4 + j] = acc[i][j];
    }
}

__global__ void reduce_partials(const float* __restrict__ Cpart, int KS,
                                const float* __restrict__ bias,
                                const float* __restrict__ bias2,
                                float* __restrict__ C, int MN, int N)
{
    int idx = blockIdx.x * 256 + threadIdx.x;
    if (idx >= MN) return;
    float v = 0.f;
    for (int z = 0; z < KS; ++z) v += Cpart[(size_t)z * MN + idx];
    int col = idx % N;
    if (bias)  v += bias[col];
    if (bias2) v += bias2[col];
    C[idx] = v;
}

// Build emb_ext (rows 0..63 = embed, row 64 = tok_emb, 65..127 = 0);
// zero negent/logp accumulators. No cross-kernel index state.
__global__ void init_k(const float* __restrict__ embed, const float* __restrict__ tok_emb,
                       float* __restrict__ emb_ext,
                       float* __restrict__ negent, float* __restrict__ logp)
{
    int i = blockIdx.x * 256 + threadIdx.x;
    if (i < 128 * E_) {
        int r = i >> 9, c = i & (E_ - 1);
        emb_ext[i] = (r < 64) ? embed[r * E_ + c] : ((r == 64) ? tok_emb[c] : 0.f);
    }
    if (i < B_) { negent[i] = 0.f; logp[i] = 0.f; }
}

// ---------------------------------------------------------------------------
// Elementwise LSTM from gathered gate rows. t==0: all rows use the SOS row
// (pointer math, no state). t>0: gates_sel[b] written by prior smax_out_k.
// 256 blocks x 256 threads; b is block-uniform per 4 blocks.
// ---------------------------------------------------------------------------
__global__ __launch_bounds__(256) void lstm_gather_k(
    const float* __restrict__ all_gates, const float* __restrict__ gates_sel,
    const float* __restrict__ hh_gates, const float* __restrict__ enc_c0,
    float* __restrict__ out_h, int t)
{
    int idx = blockIdx.x * 256 + threadIdx.x;   // B*H
    int b = idx >> 10, h = idx & (H_ - 1);
    const float* ag = (t == 0) ? (all_gates + (size_t)64 * H4_)
                               : (gates_sel + (size_t)b * H4_);
    const float* hg = hh_gates + (size_t)b * H4_;
    float gi = ag[h]           + hg[h];
    float gf = ag[H_ + h]      + hg[H_ + h];
    float gg = ag[2 * H_ + h]  + hg[2 * H_ + h];
    float go = ag[3 * H_ + h]  + hg[3 * H_ + h];
    float cc = sigm(gf) * enc_c0[idx] + sigm(gi) * tanhf(gg);
    out_h[idx] = sigm(go) * tanhf(cc);
}

// ---------------------------------------------------------------------------
// Attention scores: 512 blocks x 4 waves = 2048 waves; wave (b, sg) does 5 s.
// dec partial-sum (KS=4) + dec_b folded in registers. (validated round 8)
// ---------------------------------------------------------------------------
__global__ __launch_bounds__(256) void score_k(
    const float* __restrict__ enc_t, const float* __restrict__ dec_part,
    const float* __restrict__ dec_b, const float* __restrict__ attn_W,
    const float* __restrict__ attn_b, const int* __restrict__ lens,
    float* __restrict__ scores)
{
    const int lane = threadIdx.x & 63;
    const int gw = blockIdx.x * 4 + (threadIdx.x >> 6);   // 0..2047
    const int b = gw >> 5, sg = gw & 31;                  // 32 waves/b, 5 s each
    float dec_r[16], aw_r[16];
#pragma unroll
    for (int it = 0; it < 16; ++it) {
        int h = lane + it * 64;
        dec_r[it] = dec_part[(size_t)b * H_ + h]
                  + dec_part[(size_t)(B_ + b) * H_ + h]
                  + dec_part[(size_t)(2 * B_ + b) * H_ + h]
                  + dec_part[(size_t)(3 * B_ + b) * H_ + h]
                  + dec_b[h];
        aw_r[it] = attn_W[h];
    }
    const int len = lens[b];
    const float ab = attn_b[0];
    for (int s = sg * 5; s < sg * 5 + 5; ++s) {
        if (s >= len) { if (lane == 0) scores[b * S_ + s] = -1e9f; continue; }
        const float* ep = enc_t + ((size_t)s * B_ + b) * H_;
        float acc = 0.f;
#pragma unroll
        for (int it = 0; it < 16; ++it)
            acc += aw_r[it] * tanhf(ep[lane + it * 64] + dec_r[it]);
        for (int d = 32; d; d >>= 1) acc += __shfl_xor(acc, d);
        if (lane == 0) scores[b * S_ + s] = acc + ab;
    }
}

// ---------------------------------------------------------------------------
// Fused: softmax + attn-map out + context (float4, 4-acc ILP) + logits +
// softmax/renorm + argmax + stats + VALUE-gather of next gate row into
// gates_sel[b] (tok index stays in LDS; no cross-kernel index handoff).
// One block per b. (R8-proven tail pattern)
// ---------------------------------------------------------------------------
__global__ __launch_bounds__(256) void smax_out_k(
    const float* __restrict__ scores, const float* __restrict__ enc_out,
    const float* __restrict__ out_h, const float* __restrict__ out_W,
    const float* __restrict__ out_b, const float* __restrict__ all_gates,
    float* __restrict__ gates_sel,
    float* __restrict__ negent_acc, float* __restrict__ logp_acc,
    float* __restrict__ out, int t)
{
    __shared__ float sc[S_];
    __shared__ float comb[2 * H_];
    __shared__ float lg[V_];
    __shared__ int tok_s;
    const int tid = threadIdx.x;
    const int b = blockIdx.x;
    const int lane = tid & 63, wv = tid >> 6;
    if (wv == 0) {
        float m = -1e30f;
        for (int s = lane; s < S_; s += 64) {
            float v = scores[b * S_ + s]; sc[s] = v; m = fmaxf(m, v);
        }
        for (int d = 32; d; d >>= 1) m = fmaxf(m, __shfl_xor(m, d));
        float sum = 0.f;
        for (int s = lane; s < S_; s += 64) {
            float e = expf(sc[s] - m); sc[s] = e; sum += e;
        }
        for (int d = 32; d; d >>= 1) sum += __shfl_xor(sum, d);
        float inv = 1.f / sum;
        for (int s = lane; s < S_; s += 64) {
            float pr = sc[s] * inv; sc[s] = pr;
            out[T_ * B_ + ((size_t)b * T_ + t) * S_ + s] = pr;
        }
    }
    __syncthreads();
    {   // context: 4 h per thread, float4, 4-way ILP
        const float* base = enc_out + (size_t)b * H_ + tid * 4;
        float4 ac0 = {0,0,0,0}, ac1 = {0,0,0,0}, ac2 = {0,0,0,0}, ac3 = {0,0,0,0};
#pragma unroll 4
        for (int s = 0; s < S_; s += 4) {
            float4 e0 = *(const float4*)(base + (size_t)(s    ) * B_ * H_);
            float4 e1 = *(const float4*)(base + (size_t)(s + 1) * B_ * H_);
            float4 e2 = *(const float4*)(base + (size_t)(s + 2) * B_ * H_);
            float4 e3 = *(const float4*)(base + (size_t)(s + 3) * B_ * H_);
            float p0 = sc[s], p1 = sc[s + 1], p2 = sc[s + 2], p3 = sc[s + 3];
            ac0.x = fmaf(p0, e0.x, ac0.x); ac0.y = fmaf(p0, e0.y, ac0.y);
            ac0.z = fmaf(p0, e0.z, ac0.z); ac0.w = fmaf(p0, e0.w, ac0.w);
            ac1.x = fmaf(p1, e1.x, ac1.x); ac1.y = fmaf(p1, e1.y, ac1.y);
            ac1.z = fmaf(p1, e1.z, ac1.z); ac1.w = fmaf(p1, e1.w, ac1.w);
            ac2.x = fmaf(p2, e2.x, ac2.x); ac2.y = fmaf(p2, e2.y, ac2.y);
            ac2.z = fmaf(p2, e2.z, ac2.z); ac2.w = fmaf(p2, e2.w, ac2.w);
            ac3.x = fmaf(p3, e3.x, ac3.x); ac3.y = fmaf(p3, e3.y, ac3.y);
            ac3.z = fmaf(p3, e3.z, ac3.z); ac3.w = fmaf(p3, e3.w, ac3.w);
        }
        comb[tid * 4 + 0] = ac0.x + ac1.x + ac2.x + ac3.x;
        comb[tid * 4 + 1] = ac0.y + ac1.y + ac2.y + ac3.y;
        comb[tid * 4 + 2] = ac0.z + ac1.z + ac2.z + ac3.z;
        comb[tid * 4 + 3] = ac0.w + ac1.w + ac2.w + ac3.w;
    }
    for (int i = tid; i < H_; i += 256) comb[H_ + i] = out_h[(size_t)b * H_ + i];
    __syncthreads();
    for (int v = wv * 16; v < wv * 16 + 16; ++v) {
        const float* w = out_W + (size_t)v * (2 * H_);
        float a0 = 0.f, a1 = 0.f;
#pragma unroll
        for (int j = 0; j < 32; j += 2) {
            a0 = fmaf(comb[lane + j * 64], w[lane + j * 64], a0);
            a1 = fmaf(comb[lane + (j + 1) * 64], w[lane + (j + 1) * 64], a1);
        }
        float acc = a0 + a1;
        for (int d = 32; d; d >>= 1) acc += __shfl_xor(acc, d);
        if (lane == 0) lg[v] = acc + out_b[v];
    }
    __syncthreads();
    if (wv == 0) {
        float x = lg[lane];
        float m = x;
        for (int d = 32; d; d >>= 1) m = fmaxf(m, __shfl_xor(m, d));
        float e = expf(x - m);
        float s = e;
        for (int d = 32; d; d >>= 1) s += __shfl_xor(s, d);
        float pr = e / s;
        float ps = pr;
        for (int d = 32; d; d >>= 1) ps += __shfl_xor(ps, d);
        pr = pr / ps;   // reference renormalizes
        float bv = pr; int bi = lane;
        for (int d = 32; d; d >>= 1) {
            float ov = __shfl_xor(bv, d); int oi = __shfl_xor(bi, d);
            if (ov > bv || (ov == bv && oi < bi)) { bv = ov; bi = oi; }
        }
        float ne = pr * logf(pr + 1e-6f);
        for (int d = 32; d; d >>= 1) ne += __shfl_xor(ne, d);
        float ptok = __shfl(pr, bi);
        if (lane == 0) {
            out[t * B_ + b] = (float)bi;
            float na = negent_acc[b] + ne;                negent_acc[b] = na;
            float la = logp_acc[b] + logf(ptok + 1e-6f);  logp_acc[b] = la;
            if (t == T_ - 1) {
                out[T_ * B_ + B_ * T_ * S_ + b] = na;
                out[T_ * B_ + B_ * T_ * S_ + B_ + b] = la;
            }
            tok_s = bi;
        }
    }
    __syncthreads();
    {   // value-gather: gates_sel[b] = all_gates[tok_s]  (4096 floats, float4)
        const int tk = tok_s;
        const float4* src = (const float4*)(all_gates + (size_t)tk * H4_);
        float4* dst = (float4*)(gates_sel + (size_t)b * H4_);
        for (int i = tid; i < H4_ / 4; i += 256) dst[i] = src[i];
    }
}

extern "C" void kernel_launch(void* const* d_in, const int* in_sizes, int n_in,
                              void* d_out, int out_size, void* d_ws, size_t ws_size,
                              hipStream_t stream) {
    const float* enc_h0  = (const float*)d_in[0];
    const float* enc_c0  = (const float*)d_in[1];
    const float* enc_out = (const float*)d_in[2];
    const int*   lens    = (const int*)d_in[3];
    const float* tok_emb = (const float*)d_in[4];
    const float* embed   = (const float*)d_in[5];
    const float* W_ih    = (const float*)d_in[6];
    const float* W_hh    = (const float*)d_in[7];
    const float* b_ih    = (const float*)d_in[8];
    const float* b_hh    = (const float*)d_in[9];
    const float* out_W   = (const float*)d_in[10];
    const float* out_b   = (const float*)d_in[11];
    const float* enc_W   = (const float*)d_in[12];
    const float* enc_b   = (const float*)d_in[13];
    const float* dec_W   = (const float*)d_in[14];
    const float* dec_b   = (const float*)d_in[15];
    const float* attn_W  = (const float*)d_in[16];
    const float* attn_b  = (const float*)d_in[17];
    float* out = (float*)d_out;

    // ws layout (floats). part aliases enc_t (consumed before enc_t written).
    float* ws = (float*)d_ws;
    float* hh_gates  = ws;                         // 262144
    float* out_h     = hh_gates + B_ * H4_;        // 65536
    float* dec_part  = out_h + B_ * H_;            // 262144
    float* scores    = dec_part + 4 * B_ * H_;     // 10240
    float* negent    = scores + B_ * S_;           // 64
    float* logp      = negent + B_;                // 64
    float* gates_sel = logp + B_;                  // 262144 (B x 4H)
    float* emb_ext   = gates_sel + B_ * H4_;       // 65536 (128 x 512)
    float* all_gates = emb_ext + 128 * E_;         // 524288 (128 x 4096)
    float* enc_t     = all_gates + (size_t)128 * H4_;  // 10485760
    float* part      = enc_t;                      // alias: 4 x B x 4H
    // total = 11,937,920 floats = 47,751,680 B (ws_size known >= 49,152,512)
    if (ws_size < 47751680u) return;

    init_k<<<(128 * E_ + 255) / 256, 256, 0, stream>>>(embed, tok_emb, emb_ext,
                                                       negent, logp);

    // hh_gates = h0 @ W_hh^T + b_ih + b_hh (step-invariant)
    gemm_part<<<dim3(H4_ / 64, 1, 4), 256, 0, stream>>>(enc_h0, W_hh, part, B_, H4_, H_);
    reduce_partials<<<(B_ * H4_ + 255) / 256, 256, 0, stream>>>(
        part, 4, b_ih, b_hh, hh_gates, B_ * H4_, H4_);

    // all_gates = emb_ext @ W_ih^T (no bias; biases live in hh_gates)
    gemm_part<<<dim3(H4_ / 64, 2, 1), 256, 0, stream>>>(emb_ext, W_ih, all_gates,
                                                        128, H4_, E_);

    // enc_t = encoder_outputs @ enc_W^T + enc_b (after part consumed)
    gemm_bt_128<<<dim3(H_ / 128, (S_ * B_) / 128), 256, 0, stream>>>(
        enc_out, enc_W, enc_b, enc_t, S_ * B_, H_, H_);

    for (int t = 0; t < T_; ++t) {
        lstm_gather_k<<<(B_ * H_) / 256, 256, 0, stream>>>(all_gates, gates_sel, hh_gates,
                                                           enc_c0, out_h, t);
        gemm_part<<<dim3(H_ / 64, 1, 4), 256, 0, stream>>>(out_h, dec_W, dec_part, B_, H_, H_);
        score_k<<<512, 256, 0, stream>>>(enc_t, dec_part, dec_b, attn_W, attn_b, lens, scores);
        smax_out_k<<<64, 256, 0, stream>>>(scores, enc_out, out_h, out_W, out_b,
                                           all_gates, gates_sel, negent, logp, out, t);
    }
}